// Round 3
// baseline (116.998 us; speedup 1.0000x reference)
//
#include <hip/hip_runtime.h>
#include <math.h>

static constexpr float PI_F = 3.14159265358979323846f;

// dims: FN=16, FE=8, H=128, PQC=2, POUT=4
// workspace layout (floats):
#define WS_SEG 0      // 32*3 : segment {sum0, sum1, count}
#define WS_NF  512    // N*2  : node (a,b)
// ef2 at WS_NF + 2N : 3N float2
// P   at WS_NF + 8N : N*4

__device__ inline void rot2(float p, float t, float o, float R[2][2][2]) {
    // Rot(p,t,o) = Rz(o) Ry(t) Rz(p)
    float ct = cosf(0.5f*t), st = sinf(0.5f*t);
    float apo = 0.5f*(p+o), amo = 0.5f*(p-o);
    R[0][0][0] =  ct*cosf(apo); R[0][0][1] = -ct*sinf(apo);
    R[0][1][0] = -st*cosf(amo); R[0][1][1] = -st*sinf(amo);
    R[1][0][0] =  st*cosf(amo); R[1][0][1] = -st*sinf(amo);
    R[1][1][0] =  ct*cosf(apo); R[1][1][1] =  ct*sinf(apo);
}

__global__ __launch_bounds__(256) void k_setup(float* __restrict__ w)
{
    int tid = threadIdx.x;
    if (tid < 96) w[WS_SEG + tid] = 0.f;   // re-zero every launch
}

// --- node MLP: (N,16)@(16,128) -> leaky -> @(128,2) -> tanh*pi ---
__global__ __launch_bounds__(256) void k_node_mlp(const float* __restrict__ X,
    const float* __restrict__ W1, const float* __restrict__ b1,
    const float* __restrict__ W2, const float* __restrict__ b2,
    float2* __restrict__ nf, int N)
{
    __shared__ float sW1[16*128]; __shared__ float sb1[128];
    __shared__ float sW2a[128];   __shared__ float sW2b[128];
    __shared__ float sb2[2];
    int tid = threadIdx.x;
    for (int i = tid; i < 2048; i += 256) sW1[i] = W1[i];
    for (int i = tid; i < 128;  i += 256) { sb1[i] = b1[i]; sW2a[i] = W2[i*2+0]; sW2b[i] = W2[i*2+1]; }
    if (tid < 2) sb2[tid] = b2[tid];
    __syncthreads();
    int n = blockIdx.x * 256 + tid;
    if (n >= N) return;
    float x[16];
    const float4* xp = (const float4*)(X + (size_t)n * 16);
    float4 v0 = xp[0], v1 = xp[1], v2 = xp[2], v3 = xp[3];
    x[0]=v0.x; x[1]=v0.y; x[2]=v0.z; x[3]=v0.w;
    x[4]=v1.x; x[5]=v1.y; x[6]=v1.z; x[7]=v1.w;
    x[8]=v2.x; x[9]=v2.y; x[10]=v2.z; x[11]=v2.w;
    x[12]=v3.x; x[13]=v3.y; x[14]=v3.z; x[15]=v3.w;
    float a0 = 0.f, a1 = 0.f;
    for (int h = 0; h < 128; ++h) {
        float t = sb1[h];
        #pragma unroll
        for (int i = 0; i < 16; ++i) t = fmaf(x[i], sW1[i*128 + h], t);
        t = t > 0.f ? t : 0.01f * t;
        a0 = fmaf(t, sW2a[h], a0);
        a1 = fmaf(t, sW2b[h], a1);
    }
    float2 o;
    o.x = tanhf(a0 + sb2[0]) * PI_F;
    o.y = tanhf(a1 + sb2[1]) * PI_F;
    nf[n] = o;
}

// --- edge MLP: (3N,8)@(8,128) -> leaky -> @(128,2) -> tanh*pi ---
__global__ __launch_bounds__(256) void k_edge_mlp(const float* __restrict__ X,
    const float* __restrict__ W1, const float* __restrict__ b1,
    const float* __restrict__ W2, const float* __restrict__ b2,
    float2* __restrict__ ef2, int NE)
{
    __shared__ float sW1[8*128]; __shared__ float sb1[128];
    __shared__ float sW2a[128];  __shared__ float sW2b[128];
    __shared__ float sb2[2];
    int tid = threadIdx.x;
    for (int i = tid; i < 1024; i += 256) sW1[i] = W1[i];
    for (int i = tid; i < 128;  i += 256) { sb1[i] = b1[i]; sW2a[i] = W2[i*2+0]; sW2b[i] = W2[i*2+1]; }
    if (tid < 2) sb2[tid] = b2[tid];
    __syncthreads();
    int e = blockIdx.x * 256 + tid;
    if (e >= NE) return;
    float x[8];
    const float4* xp = (const float4*)(X + (size_t)e * 8);
    float4 v0 = xp[0], v1 = xp[1];
    x[0]=v0.x; x[1]=v0.y; x[2]=v0.z; x[3]=v0.w;
    x[4]=v1.x; x[5]=v1.y; x[6]=v1.z; x[7]=v1.w;
    float acc0 = 0.f, acc1 = 0.f;
    for (int h = 0; h < 128; ++h) {
        float t = sb1[h];
        #pragma unroll
        for (int i = 0; i < 8; ++i) t = fmaf(x[i], sW1[i*128 + h], t);
        t = t > 0.f ? t : 0.01f * t;
        acc0 = fmaf(t, sW2a[h], acc0);
        acc1 = fmaf(t, sW2b[h], acc1);
    }
    float2 o;
    o.x = tanhf(acc0 + sb2[0]) * PI_F;
    o.y = tanhf(acc1 + sb2[1]) * PI_F;
    ef2[e] = o;
}

// complex 2x2 gate helpers on (u,w) amplitude pair (target = wire 7)
#define APPLY_RX(ur,ui,wr,wi) { \
    float tur = cx*ur + sx*wi, tui = cx*ui - sx*wr; \
    float twr = sx*ui + cx*wr, twi = -sx*ur + cx*wi; \
    ur=tur; ui=tui; wr=twr; wi=twi; }
#define APPLY_RY(ur,ui,wr,wi) { \
    float tur = cy*ur - sy*wr, tui = cy*ui - sy*wi; \
    float twr = sy*ur + cy*wr, twi = sy*ui + cy*wi; \
    ur=tur; ui=tui; wr=twr; wi=twi; }
#define APPLY_RZ(ur,ui,wr,wi) { \
    float tur = cz*ur + sz*ui, tui = cz*ui - sz*ur; \
    float twr = cz*wr - sz*wi, twi = cz*wi + sz*wr; \
    ur=tur; ui=tui; wr=twr; wi=twi; }

// --- brute-force circuit: one wave per node, 256 amps = 4/lane ---
// amp a = lane*4 + r ; w0..w5 <-> lane bits 5..0 ; w6 <-> r bit1 ; w7 <-> r bit0
__global__ __launch_bounds__(256) void k_brute(const float2* __restrict__ nf,
    const float2* __restrict__ ef2,
    const float* __restrict__ inits, const float* __restrict__ update,
    const int* __restrict__ sub_nodes, const int* __restrict__ sub_edges,
    float* __restrict__ Pout, int N)
{
    int lane = threadIdx.x & 63;
    int n = blockIdx.x * 4 + (threadIdx.x >> 6);
    if (n >= N) return;

    const int* sn = sub_nodes + (size_t)n * 4;
    const int* se = sub_edges + (size_t)n * 3;
    float aw[7], bw[7];
    #pragma unroll
    for (int j = 0; j < 3; ++j) { float2 e = ef2[se[j]]; aw[j] = e.x; bw[j] = e.y; }
    {   float2 c = nf[sn[0]]; aw[3] = c.x; bw[3] = c.y; }
    #pragma unroll
    for (int j = 0; j < 3; ++j) { float2 c = nf[sn[1+j]]; aw[4+j] = c.x; bw[4+j] = c.y; }
    // per-wire qubit: q0 = e^{-ib/2} cos(a/2), q1 = e^{+ib/2} sin(a/2)
    float q0r[7], q0i[7], q1r[7], q1i[7];
    #pragma unroll
    for (int wv = 0; wv < 7; ++wv) {
        float ca = cosf(0.5f*aw[wv]), sa = sinf(0.5f*aw[wv]);
        float cb = cosf(0.5f*bw[wv]), sb = sinf(0.5f*bw[wv]);
        q0r[wv] = cb*ca; q0i[wv] = -sb*ca;
        q1r[wv] = cb*sa; q1i[wv] =  sb*sa;
    }
    // initial product over wires 0..5 (lane bits 5..0)
    float pr_ = 1.f, pi_ = 0.f;
    #pragma unroll
    for (int wv = 0; wv < 6; ++wv) {
        int bit = (lane >> (5 - wv)) & 1;
        float cr = bit ? q1r[wv] : q0r[wv];
        float ci = bit ? q1i[wv] : q0i[wv];
        float nr = pr_*cr - pi_*ci, ni = pr_*ci + pi_*cr;
        pr_ = nr; pi_ = ni;
    }
    // slots r=0..3: (w6,w7) = (r>>1, r&1); wire7 |0> -> odd slots zero
    float v0r = pr_*q0r[6] - pi_*q0i[6], v0i = pr_*q0i[6] + pi_*q0r[6];
    float v2r = pr_*q1r[6] - pi_*q1i[6], v2i = pr_*q1i[6] + pi_*q1r[6];
    float v1r = 0.f, v1i = 0.f, v3r = 0.f, v3i = 0.f;

    float cx = cosf(0.5f*inits[0]), sx = sinf(0.5f*inits[0]);
    float cy = cosf(0.5f*inits[1]), sy = sinf(0.5f*inits[1]);
    float cz = cosf(0.5f*inits[2]), sz = sinf(0.5f*inits[2]);
    {   // i = 0: CRX/CRZ ctrl w4 (lane bit1), CRY ctrl w0 (lane bit5)
        bool xc = (lane >> 1) & 1, yc = (lane >> 5) & 1;
        if (xc) { APPLY_RX(v0r,v0i,v1r,v1i); APPLY_RX(v2r,v2i,v3r,v3i); }
        if (yc) { APPLY_RY(v0r,v0i,v1r,v1i); APPLY_RY(v2r,v2i,v3r,v3i); }
        if (xc) { APPLY_RZ(v0r,v0i,v1r,v1i); APPLY_RZ(v2r,v2i,v3r,v3i); }
    }
    {   // i = 1: ctrl w5 (lane bit0), CRY ctrl w1 (lane bit4)
        bool xc = lane & 1, yc = (lane >> 4) & 1;
        if (xc) { APPLY_RX(v0r,v0i,v1r,v1i); APPLY_RX(v2r,v2i,v3r,v3i); }
        if (yc) { APPLY_RY(v0r,v0i,v1r,v1i); APPLY_RY(v2r,v2i,v3r,v3i); }
        if (xc) { APPLY_RZ(v0r,v0i,v1r,v1i); APPLY_RZ(v2r,v2i,v3r,v3i); }
    }
    {   // i = 2: ctrl w6 (r bit1 -> only v2/v3 pair), CRY ctrl w2 (lane bit3)
        bool yc = (lane >> 3) & 1;
        APPLY_RX(v2r,v2i,v3r,v3i);
        if (yc) { APPLY_RY(v0r,v0i,v1r,v1i); APPLY_RY(v2r,v2i,v3r,v3i); }
        APPLY_RZ(v2r,v2i,v3r,v3i);
    }

    // Rot on wire3 (lane bit2, xor 4) and wire7 (in-register)
    float Ra[2][2][2], Rb[2][2][2];
    rot2(update[0], update[1], update[2], Ra);
    rot2(update[3], update[4], update[5], Rb);
    int b3 = (lane >> 2) & 1;
    float daar = b3 ? Ra[1][1][0] : Ra[0][0][0];
    float daai = b3 ? Ra[1][1][1] : Ra[0][0][1];
    float dabr = b3 ? Ra[1][0][0] : Ra[0][1][0];
    float dabi = b3 ? Ra[1][0][1] : Ra[0][1][1];
#define ROT3(vr, vi) { \
    float pvr = __shfl_xor(vr, 4), pvi = __shfl_xor(vi, 4); \
    float nr = daar*vr - daai*vi + dabr*pvr - dabi*pvi; \
    float ni = daar*vi + daai*vr + dabr*pvi + dabi*pvr; \
    vr = nr; vi = ni; }
    ROT3(v0r, v0i); ROT3(v1r, v1i); ROT3(v2r, v2i); ROT3(v3r, v3i);
#define ROT7(ur,ui,wr,wi) { \
    float n0r = Rb[0][0][0]*ur - Rb[0][0][1]*ui + Rb[0][1][0]*wr - Rb[0][1][1]*wi; \
    float n0i = Rb[0][0][0]*ui + Rb[0][0][1]*ur + Rb[0][1][0]*wi + Rb[0][1][1]*wr; \
    float n1r = Rb[1][0][0]*ur - Rb[1][0][1]*ui + Rb[1][1][0]*wr - Rb[1][1][1]*wi; \
    float n1i = Rb[1][0][0]*ui + Rb[1][0][1]*ur + Rb[1][1][0]*wi + Rb[1][1][1]*wr; \
    ur=n0r; ui=n0i; wr=n1r; wi=n1i; }
    ROT7(v0r,v0i,v1r,v1i); ROT7(v2r,v2i,v3r,v3i);
    // CNOT(3,7): lanes with w3=1 swap w7 pairs
    if (b3) {
        float t;
        t=v0r; v0r=v1r; v1r=t;  t=v0i; v0i=v1i; v1i=t;
        t=v2r; v2r=v3r; v3r=t;  t=v2i; v2i=v3i; v3i=t;
    }
    // CNOT(7,3): slots with w7=1 (r=1,3) swap across lane xor 4
    v1r = __shfl_xor(v1r, 4); v1i = __shfl_xor(v1i, 4);
    v3r = __shfl_xor(v3r, 4); v3i = __shfl_xor(v3i, 4);

    // probabilities: k = 2*w3 + w7
    float pl0 = v0r*v0r + v0i*v0i + v2r*v2r + v2i*v2i;
    float pl1 = v1r*v1r + v1i*v1i + v3r*v3r + v3i*v3i;
    float a0 = b3 ? 0.f : pl0, a1 = b3 ? 0.f : pl1;
    float a2 = b3 ? pl0 : 0.f, a3 = b3 ? pl1 : 0.f;
    #pragma unroll
    for (int off = 32; off >= 1; off >>= 1) {
        a0 += __shfl_xor(a0, off); a1 += __shfl_xor(a1, off);
        a2 += __shfl_xor(a2, off); a3 += __shfl_xor(a3, off);
    }
    if (lane == 0) ((float4*)Pout)[n] = make_float4(a0, a1, a2, a3);
}

// --- epilogue: upd MLP (6->128->2) + x + LayerNorm(2) + segment accumulate ---
__global__ __launch_bounds__(256) void k_post(const float2* __restrict__ nf,
    const float* __restrict__ Pin,
    const float* __restrict__ uW1, const float* __restrict__ ub1,
    const float* __restrict__ uW2, const float* __restrict__ ub2,
    const float* __restrict__ lng, const float* __restrict__ lnb,
    const int* __restrict__ batch, float* __restrict__ seg, int N)
{
    __shared__ float sW1[6*128]; __shared__ float sb1[128];
    __shared__ float sW2a[128];  __shared__ float sW2b[128];
    __shared__ float sb2[2]; __shared__ float sg[2]; __shared__ float sbeta[2];
    __shared__ float sseg[32*3];
    int tid = threadIdx.x;
    for (int i = tid; i < 768; i += 256) sW1[i] = uW1[i];
    for (int i = tid; i < 128;  i += 256) { sb1[i] = ub1[i]; sW2a[i] = uW2[i*2+0]; sW2b[i] = uW2[i*2+1]; }
    if (tid < 2) { sb2[tid] = ub2[tid]; sg[tid] = lng[tid]; sbeta[tid] = lnb[tid]; }
    for (int i = tid; i < 96; i += 256) sseg[i] = 0.f;
    __syncthreads();

    int n = blockIdx.x * 256 + tid;
    if (n < N) {
        float2 nfc = nf[n];                    // centers == arange(N)
        float4 Pq  = ((const float4*)Pin)[n];
        float in6[6] = {nfc.x, nfc.y, Pq.x, Pq.y, Pq.z, Pq.w};
        float u0 = 0.f, u1 = 0.f;
        for (int h = 0; h < 128; ++h) {
            float t = sb1[h];
            #pragma unroll
            for (int i = 0; i < 6; ++i) t = fmaf(in6[i], sW1[i*128 + h], t);
            t = t > 0.f ? t : 0.01f * t;
            u0 = fmaf(t, sW2a[h], u0);
            u1 = fmaf(t, sW2b[h], u1);
        }
        // x = 1.5*nf + 0.5*upd
        float x0 = 1.5f*nfc.x + 0.5f * (tanhf(u0 + sb2[0]) * PI_F);
        float x1 = 1.5f*nfc.y + 0.5f * (tanhf(u1 + sb2[1]) * PI_F);
        // LayerNorm over 2 features
        float mu = 0.5f * (x0 + x1);
        float d  = x0 - mu;                    // = (x0-x1)/2 ; x1-mu = -d
        float var = d * d;                     // mean of (±d)^2
        float inv = 1.0f / sqrtf(var + 1e-5f);
        float xn0 =  d * inv * sg[0] + sbeta[0];
        float xn1 = -d * inv * sg[1] + sbeta[1];
        int bs = batch[n];
        atomicAdd(&sseg[bs*3 + 0], xn0);
        atomicAdd(&sseg[bs*3 + 1], xn1);
        atomicAdd(&sseg[bs*3 + 2], 1.0f);
    }
    __syncthreads();
    for (int i = tid; i < 96; i += 256) atomicAdd(&seg[i], sseg[i]);
}

// --- head MLP on 32 segment means: (32,2)@(2,2) leaky @(2,2) ---
__global__ void k_head(const float* __restrict__ seg,
                       const float* __restrict__ W1, const float* __restrict__ b1,
                       const float* __restrict__ W2, const float* __restrict__ b2,
                       float* __restrict__ out)
{
    int s = threadIdx.x;
    if (s >= 32) return;
    float cnt = seg[s*3+2];
    float inv = cnt > 0.f ? 1.0f / cnt : 0.f;
    float g0 = seg[s*3+0]*inv, g1 = seg[s*3+1]*inv;
    float h[2];
    #pragma unroll
    for (int j = 0; j < 2; ++j) {
        float t = b1[j] + g0*W1[0*2+j] + g1*W1[1*2+j];
        h[j] = t > 0.f ? t : 0.01f * t;
    }
    #pragma unroll
    for (int k = 0; k < 2; ++k)
        out[s*2+k] = b2[k] + h[0]*W2[0*2+k] + h[1]*W2[1*2+k];
}

extern "C" void kernel_launch(void* const* d_in, const int* in_sizes, int n_in,
                              void* d_out, int out_size, void* d_ws, size_t ws_size,
                              hipStream_t stream)
{
    const float* node_feat = (const float*)d_in[0];
    const float* edge_attr = (const float*)d_in[1];
    const float* node_W1 = (const float*)d_in[2];
    const float* node_b1 = (const float*)d_in[3];
    const float* node_W2 = (const float*)d_in[4];
    const float* node_b2 = (const float*)d_in[5];
    const float* edge_W1 = (const float*)d_in[6];
    const float* edge_b1 = (const float*)d_in[7];
    const float* edge_W2 = (const float*)d_in[8];
    const float* edge_b2 = (const float*)d_in[9];
    const float* inits   = (const float*)d_in[10];
    const float* update  = (const float*)d_in[11];
    const float* upd_W1  = (const float*)d_in[12];
    const float* upd_b1  = (const float*)d_in[13];
    const float* upd_W2  = (const float*)d_in[14];
    const float* upd_b2  = (const float*)d_in[15];
    const float* ln_g    = (const float*)d_in[16];
    const float* ln_b    = (const float*)d_in[17];
    const float* head_W1 = (const float*)d_in[18];
    const float* head_b1 = (const float*)d_in[19];
    const float* head_W2 = (const float*)d_in[20];
    const float* head_b2 = (const float*)d_in[21];
    const int* sub_nodes = (const int*)d_in[22];
    const int* sub_edges = (const int*)d_in[23];
    const int* batch     = (const int*)d_in[24];

    int N  = in_sizes[24];      // 32768 nodes
    int NE = in_sizes[1] / 8;   // 98304 edges

    float* w    = (float*)d_ws;
    float2* nf  = (float2*)(w + WS_NF);
    float2* ef2 = (float2*)(w + WS_NF + (size_t)N * 2);
    float* P    = w + WS_NF + (size_t)N * 8;
    size_t need = ((size_t)WS_NF + (size_t)N * 12) * sizeof(float);
    if (ws_size < need) return;

    k_setup<<<1, 256, 0, stream>>>(w);
    k_node_mlp<<<(N + 255) / 256, 256, 0, stream>>>(node_feat, node_W1, node_b1, node_W2, node_b2, nf, N);
    k_edge_mlp<<<(NE + 255) / 256, 256, 0, stream>>>(edge_attr, edge_W1, edge_b1, edge_W2, edge_b2, ef2, NE);
    k_brute<<<(N + 3) / 4, 256, 0, stream>>>(nf, ef2, inits, update, sub_nodes, sub_edges, P, N);
    k_post<<<(N + 255) / 256, 256, 0, stream>>>(nf, P, upd_W1, upd_b1, upd_W2, upd_b2,
                                                ln_g, ln_b, batch, w + WS_SEG, N);
    k_head<<<1, 64, 0, stream>>>(w + WS_SEG, head_W1, head_b1, head_W2, head_b2, (float*)d_out);
}

// Round 4
// 44.445 us; speedup vs baseline: 2.6324x; 2.6324x over previous
//
#include <hip/hip_runtime.h>
#include <math.h>

static constexpr float PI_F = 3.14159265358979323846f;

// dims: N=32768 nodes, NE=3N edges, H=128, PQC=2
// ws layout (floats):
//   [0..96)    seg: 32 x {sum0, sum1, count}
//   [96]       int counter (last-block election)
//   [128..384) phi table: 64 x {|p0|^2, |p1|^2, Re(p0 p1*), Im(p0 p1*)}
//   [384..416) U: 4x4 complex row-major [k][c][re,im]
//   [512..512+2N)      nf  (float2 per node: a,b)
//   [512+2N..512+2N+NE) ef1 (edge a only; edge b provably drops out)

__device__ inline void rot2(float p, float t, float o, float R[2][2][2]) {
    // Rot(p,t,o) = Rz(o) Ry(t) Rz(p)
    float ct = cosf(0.5f*t), st = sinf(0.5f*t);
    float apo = 0.5f*(p+o), amo = 0.5f*(p-o);
    R[0][0][0] =  ct*cosf(apo); R[0][0][1] = -ct*sinf(apo);
    R[0][1][0] = -st*cosf(amo); R[0][1][1] = -st*sinf(amo);
    R[1][0][0] =  st*cosf(amo); R[1][0][1] = -st*sinf(amo);
    R[1][1][0] =  ct*cosf(apo); R[1][1][1] =  ct*sinf(apo);
}

// --- kernel A: setup (block 0) + edge MLP (blocks [0,nbE)) + node MLP (rest) ---
// Weights read directly from global with wave-uniform indices -> s_load (no LDS).
__global__ __launch_bounds__(256) void k_mlp(
    const float* __restrict__ node_feat, const float* __restrict__ edge_attr,
    const float* __restrict__ nW1, const float* __restrict__ nb1,
    const float* __restrict__ nW2, const float* __restrict__ nb2,
    const float* __restrict__ eW1, const float* __restrict__ eb1,
    const float* __restrict__ eW2, const float* __restrict__ eb2,
    const float* __restrict__ inits, const float* __restrict__ update,
    float* __restrict__ ws, int N, int NE, int nbE)
{
    const int tid = threadIdx.x;
    const int blk = blockIdx.x;

    if (blk == 0) {
        // zero segment accumulators + counter (harness doesn't re-poison between replays)
        if (tid < 96) ws[tid] = 0.f;
        if (tid == 96) ((int*)ws)[96] = 0;
        if (tid < 64) {
            // phi table: wire-7 state for control pattern tid
            // bits 0..2 = wires 0,1,2 (CRY ctrl), bits 3..5 = wires 4,5,6 (CRX/CRZ ctrl)
            float cx = cosf(0.5f*inits[0]), sx = sinf(0.5f*inits[0]);
            float cy = cosf(0.5f*inits[1]), sy = sinf(0.5f*inits[1]);
            float cz = cosf(0.5f*inits[2]), sz = sinf(0.5f*inits[2]);
            float v0r = 1.f, v0i = 0.f, v1r = 0.f, v1i = 0.f;
            #pragma unroll
            for (int i = 0; i < 3; ++i) {
                int xb = (tid >> (3+i)) & 1;
                int yb = (tid >> i) & 1;
                if (xb) { // Rx
                    float n0r = cx*v0r + sx*v1i, n0i = cx*v0i - sx*v1r;
                    float n1r = sx*v0i + cx*v1r, n1i = -sx*v0r + cx*v1i;
                    v0r=n0r; v0i=n0i; v1r=n1r; v1i=n1i;
                }
                if (yb) { // Ry
                    float n0r = cy*v0r - sy*v1r, n0i = cy*v0i - sy*v1i;
                    float n1r = sy*v0r + cy*v1r, n1i = sy*v0i + cy*v1i;
                    v0r=n0r; v0i=n0i; v1r=n1r; v1i=n1i;
                }
                if (xb) { // Rz
                    float n0r = cz*v0r + sz*v0i, n0i = cz*v0i - sz*v0r;
                    float n1r = cz*v1r - sz*v1i, n1i = cz*v1i + sz*v1r;
                    v0r=n0r; v0i=n0i; v1r=n1r; v1i=n1i;
                }
            }
            ws[128 + tid*4 + 0] = v0r*v0r + v0i*v0i;
            ws[128 + tid*4 + 1] = v1r*v1r + v1i*v1i;
            ws[128 + tid*4 + 2] = v0r*v1r + v0i*v1i;   // Re(p0 p1*)
            ws[128 + tid*4 + 3] = v0i*v1r - v0r*v1i;   // Im(p0 p1*)
        } else if (tid == 64) {
            // U = CNOT(7,3) CNOT(3,7) (Ra (x) Rb), basis idx = 2*w3 + w7; row perm {0,2,3,1}
            float Ra[2][2][2], Rb[2][2][2];
            rot2(update[0], update[1], update[2], Ra);
            rot2(update[3], update[4], update[5], Rb);
            const int src[4] = {0, 2, 3, 1};
            #pragma unroll
            for (int k = 0; k < 4; ++k) {
                int r = src[k], r3 = r >> 1, r7 = r & 1;
                #pragma unroll
                for (int c = 0; c < 4; ++c) {
                    int c3 = c >> 1, c7 = c & 1;
                    float ar = Ra[r3][c3][0], ai = Ra[r3][c3][1];
                    float br = Rb[r7][c7][0], bi = Rb[r7][c7][1];
                    ws[384 + (k*4+c)*2 + 0] = ar*br - ai*bi;
                    ws[384 + (k*4+c)*2 + 1] = ar*bi + ai*br;
                }
            }
        }
    }

    if (blk < nbE) {
        // ---- edge MLP: (8->128->1), only output col 0 (edge b drops out of circuit) ----
        int e = blk * 256 + tid;
        if (e >= NE) return;
        const float4* xp = (const float4*)(edge_attr + (size_t)e * 8);
        float4 v0 = xp[0], v1 = xp[1];
        float x[8] = {v0.x,v0.y,v0.z,v0.w, v1.x,v1.y,v1.z,v1.w};
        float t[128];
        #pragma unroll
        for (int h = 0; h < 128; ++h) t[h] = eb1[h];
        #pragma unroll
        for (int i = 0; i < 8; ++i) {
            const float* row = eW1 + i*128;
            float xi = x[i];
            #pragma unroll
            for (int h = 0; h < 128; ++h) t[h] = fmaf(xi, row[h], t[h]);
        }
        float acc = 0.f;
        #pragma unroll
        for (int h = 0; h < 128; ++h) {
            float lt = t[h] > 0.f ? t[h] : 0.01f * t[h];
            acc = fmaf(lt, eW2[2*h], acc);
        }
        ws[512 + 2*(size_t)N + e] = tanhf(acc + eb2[0]) * PI_F;
    } else {
        // ---- node MLP: (16->128->2) ----
        int n = (blk - nbE) * 256 + tid;
        if (n >= N) return;
        const float4* xp = (const float4*)(node_feat + (size_t)n * 16);
        float4 v0 = xp[0], v1 = xp[1], v2 = xp[2], v3 = xp[3];
        float x[16] = {v0.x,v0.y,v0.z,v0.w, v1.x,v1.y,v1.z,v1.w,
                       v2.x,v2.y,v2.z,v2.w, v3.x,v3.y,v3.z,v3.w};
        float t[128];
        #pragma unroll
        for (int h = 0; h < 128; ++h) t[h] = nb1[h];
        #pragma unroll
        for (int i = 0; i < 16; ++i) {
            const float* row = nW1 + i*128;
            float xi = x[i];
            #pragma unroll
            for (int h = 0; h < 128; ++h) t[h] = fmaf(xi, row[h], t[h]);
        }
        float a0 = 0.f, a1 = 0.f;
        #pragma unroll
        for (int h = 0; h < 128; ++h) {
            float lt = t[h] > 0.f ? t[h] : 0.01f * t[h];
            a0 = fmaf(lt, nW2[2*h],   a0);
            a1 = fmaf(lt, nW2[2*h+1], a1);
        }
        float2 o;
        o.x = tanhf(a0 + nb2[0]) * PI_F;
        o.y = tanhf(a1 + nb2[1]) * PI_F;
        ((float2*)(ws + 512))[n] = o;
    }
}

// --- kernel B: analytic circuit + upd MLP + LN + segment reduce + (last block) head ---
__global__ __launch_bounds__(256) void k_circ(
    float* __restrict__ ws,
    const float* __restrict__ uW1, const float* __restrict__ ub1,
    const float* __restrict__ uW2, const float* __restrict__ ub2,
    const float* __restrict__ lng, const float* __restrict__ lnb,
    const int* __restrict__ sub_nodes, const int* __restrict__ sub_edges,
    const int* __restrict__ batch,
    const float* __restrict__ hW1, const float* __restrict__ hb1,
    const float* __restrict__ hW2, const float* __restrict__ hb2,
    float* __restrict__ out, int N)
{
    const int tid = threadIdx.x;
    const float2* nf  = (const float2*)(ws + 512);
    const float* ef1  = ws + 512 + 2*(size_t)N;
    const float4* phi4 = (const float4*)(ws + 128);
    const float* U    = ws + 384;

    int n0 = blockIdx.x * 256 + tid;
    bool valid = n0 < N;
    int n = valid ? n0 : N - 1;

    const int4 sn = ((const int4*)sub_nodes)[n];
    int se0 = sub_edges[3*(size_t)n+0], se1 = sub_edges[3*(size_t)n+1], se2 = sub_edges[3*(size_t)n+2];

    // control-wire probability weights (only a-angle matters; cos^2(a/2)=(1+cos a)/2)
    float pe[3][2], pn[3][2];
    {
        float c0 = cosf(ef1[se0]), c1 = cosf(ef1[se1]), c2 = cosf(ef1[se2]);
        pe[0][0]=0.5f*(1.f+c0); pe[0][1]=0.5f*(1.f-c0);
        pe[1][0]=0.5f*(1.f+c1); pe[1][1]=0.5f*(1.f-c1);
        pe[2][0]=0.5f*(1.f+c2); pe[2][1]=0.5f*(1.f-c2);
        float d0 = cosf(nf[sn.y].x), d1 = cosf(nf[sn.z].x), d2 = cosf(nf[sn.w].x);
        pn[0][0]=0.5f*(1.f+d0); pn[0][1]=0.5f*(1.f-d0);
        pn[1][0]=0.5f*(1.f+d1); pn[1][1]=0.5f*(1.f-d1);
        pn[2][0]=0.5f*(1.f+d2); pn[2][1]=0.5f*(1.f-d2);
    }
    float E[8], Nw[8];
    #pragma unroll
    for (int m = 0; m < 8; ++m) {
        E[m]  = pe[0][m&1] * pe[1][(m>>1)&1] * pe[2][(m>>2)&1];
        Nw[m] = pn[0][m&1] * pn[1][(m>>1)&1] * pn[2][(m>>2)&1];
    }
    float S0 = 0.f, S1 = 0.f, Sr = 0.f, Si = 0.f;
    #pragma unroll
    for (int m = 0; m < 64; ++m) {
        float W = E[m & 7] * Nw[m >> 3];
        float4 g = phi4[m];
        S0 = fmaf(W, g.x, S0); S1 = fmaf(W, g.y, S1);
        Sr = fmaf(W, g.z, Sr); Si = fmaf(W, g.w, Si);
    }
    // center qubit + T = U (q3 (x) I)
    float2 nfc = nf[sn.x];
    float ca = cosf(0.5f*nfc.x), sa = sinf(0.5f*nfc.x);
    float cb = cosf(0.5f*nfc.y), sb = sinf(0.5f*nfc.y);
    float q0r = ca*cb, q0i = -ca*sb, q1r = sa*cb, q1i = sa*sb;
    float P[4];
    #pragma unroll
    for (int k = 0; k < 4; ++k) {
        float T0r, T0i, T1r, T1i;
        {
            float u0r = U[(k*4+0)*2], u0i = U[(k*4+0)*2+1];
            float u1r = U[(k*4+2)*2], u1i = U[(k*4+2)*2+1];
            T0r = u0r*q0r - u0i*q0i + u1r*q1r - u1i*q1i;
            T0i = u0r*q0i + u0i*q0r + u1r*q1i + u1i*q1r;
        }
        {
            float u0r = U[(k*4+1)*2], u0i = U[(k*4+1)*2+1];
            float u1r = U[(k*4+3)*2], u1i = U[(k*4+3)*2+1];
            T1r = u0r*q0r - u0i*q0i + u1r*q1r - u1i*q1i;
            T1i = u0r*q0i + u0i*q0r + u1r*q1i + u1i*q1r;
        }
        float Ar = T0r*T1r + T0i*T1i, Ai = T0i*T1r - T0r*T1i;
        P[k] = (T0r*T0r + T0i*T0i)*S0 + (T1r*T1r + T1i*T1i)*S1 + 2.f*(Ar*Sr - Ai*Si);
    }
    // upd MLP (6->128->2), weights via uniform s_load
    float in6[6] = {nfc.x, nfc.y, P[0], P[1], P[2], P[3]};
    float t[128];
    #pragma unroll
    for (int h = 0; h < 128; ++h) t[h] = ub1[h];
    #pragma unroll
    for (int i = 0; i < 6; ++i) {
        const float* row = uW1 + i*128;
        float xi = in6[i];
        #pragma unroll
        for (int h = 0; h < 128; ++h) t[h] = fmaf(xi, row[h], t[h]);
    }
    float u0 = 0.f, u1 = 0.f;
    #pragma unroll
    for (int h = 0; h < 128; ++h) {
        float lt = t[h] > 0.f ? t[h] : 0.01f * t[h];
        u0 = fmaf(lt, uW2[2*h],   u0);
        u1 = fmaf(lt, uW2[2*h+1], u1);
    }
    // x = 1.5*nf + 0.5*upd (centers == arange(N)); LayerNorm over 2 features
    float x0 = 1.5f*nfc.x + 0.5f*(tanhf(u0 + ub2[0]) * PI_F);
    float x1 = 1.5f*nfc.y + 0.5f*(tanhf(u1 + ub2[1]) * PI_F);
    float mu = 0.5f*(x0 + x1);
    float d  = x0 - mu;
    float inv = 1.0f / sqrtf(d*d + 1e-5f);
    float wv  = valid ? 1.f : 0.f;
    float xn0 = ( d*inv*lng[0] + lnb[0]) * wv;
    float xn1 = (-d*inv*lng[1] + lnb[1]) * wv;
    int bs = batch[n];

    // segment accumulate: wave-uniform fast path (batch is sorted), per-lane fallback
    bool uni = __all(bs == __shfl(bs, 0));
    if (uni) {
        float r0 = xn0, r1 = xn1, rc = wv;
        #pragma unroll
        for (int off = 32; off >= 1; off >>= 1) {
            r0 += __shfl_xor(r0, off); r1 += __shfl_xor(r1, off); rc += __shfl_xor(rc, off);
        }
        if ((tid & 63) == 0) {
            atomicAdd(&ws[bs*3+0], r0);
            atomicAdd(&ws[bs*3+1], r1);
            atomicAdd(&ws[bs*3+2], rc);
        }
    } else if (valid) {
        atomicAdd(&ws[bs*3+0], xn0);
        atomicAdd(&ws[bs*3+1], xn1);
        atomicAdd(&ws[bs*3+2], 1.f);
    }

    // last-block election -> head MLP (2->2 leaky 2->2) on segment means
    __shared__ int sLast;
    __threadfence();
    __syncthreads();
    if (tid == 0) {
        int old = atomicAdd((int*)ws + 96, 1);
        sLast = (old == (int)gridDim.x - 1) ? 1 : 0;
    }
    __syncthreads();
    if (sLast && tid < 32) {
        // device-scope atomic reads for cross-XCD coherence
        float cnt = atomicAdd(&ws[tid*3+2], 0.f);
        float iv  = cnt > 0.f ? 1.f/cnt : 0.f;
        float g0  = atomicAdd(&ws[tid*3+0], 0.f) * iv;
        float g1  = atomicAdd(&ws[tid*3+1], 0.f) * iv;
        float h0, h1;
        {
            float a = hb1[0] + g0*hW1[0] + g1*hW1[2];
            float b = hb1[1] + g0*hW1[1] + g1*hW1[3];
            h0 = a > 0.f ? a : 0.01f*a;
            h1 = b > 0.f ? b : 0.01f*b;
        }
        out[tid*2+0] = hb2[0] + h0*hW2[0] + h1*hW2[2];
        out[tid*2+1] = hb2[1] + h0*hW2[1] + h1*hW2[3];
    }
}

extern "C" void kernel_launch(void* const* d_in, const int* in_sizes, int n_in,
                              void* d_out, int out_size, void* d_ws, size_t ws_size,
                              hipStream_t stream)
{
    const float* node_feat = (const float*)d_in[0];
    const float* edge_attr = (const float*)d_in[1];
    const float* node_W1 = (const float*)d_in[2];
    const float* node_b1 = (const float*)d_in[3];
    const float* node_W2 = (const float*)d_in[4];
    const float* node_b2 = (const float*)d_in[5];
    const float* edge_W1 = (const float*)d_in[6];
    const float* edge_b1 = (const float*)d_in[7];
    const float* edge_W2 = (const float*)d_in[8];
    const float* edge_b2 = (const float*)d_in[9];
    const float* inits   = (const float*)d_in[10];
    const float* update  = (const float*)d_in[11];
    const float* upd_W1  = (const float*)d_in[12];
    const float* upd_b1  = (const float*)d_in[13];
    const float* upd_W2  = (const float*)d_in[14];
    const float* upd_b2  = (const float*)d_in[15];
    const float* ln_g    = (const float*)d_in[16];
    const float* ln_b    = (const float*)d_in[17];
    const float* head_W1 = (const float*)d_in[18];
    const float* head_b1 = (const float*)d_in[19];
    const float* head_W2 = (const float*)d_in[20];
    const float* head_b2 = (const float*)d_in[21];
    const int* sub_nodes = (const int*)d_in[22];
    const int* sub_edges = (const int*)d_in[23];
    const int* batch     = (const int*)d_in[24];

    int N  = in_sizes[24];      // 32768
    int NE = in_sizes[1] / 8;   // 98304

    float* w = (float*)d_ws;
    size_t need = (512 + 2*(size_t)N + (size_t)NE) * sizeof(float);
    if (ws_size < need) return;

    int nbE = (NE + 255) / 256;
    int nbN = (N + 255) / 256;
    k_mlp<<<nbE + nbN, 256, 0, stream>>>(node_feat, edge_attr,
        node_W1, node_b1, node_W2, node_b2,
        edge_W1, edge_b1, edge_W2, edge_b2,
        inits, update, w, N, NE, nbE);
    k_circ<<<nbN, 256, 0, stream>>>(w,
        upd_W1, upd_b1, upd_W2, upd_b2, ln_g, ln_b,
        sub_nodes, sub_edges, batch,
        head_W1, head_b1, head_W2, head_b2,
        (float*)d_out, N);
}